// Round 5
// baseline (166.222 us; speedup 1.0000x reference)
//
#include <hip/hip_runtime.h>
#include <stdint.h>

#define S_LEN 2048
#define NHEADS 16
#define DHEAD 64
#define DMODEL 1024

typedef unsigned short u16;
typedef unsigned int u32;
typedef __bf16 bf16x8 __attribute__((ext_vector_type(8)));
typedef float f32x4 __attribute__((ext_vector_type(4)));
typedef float f32x16 __attribute__((ext_vector_type(16)));
typedef u32 u32x4 __attribute__((ext_vector_type(4)));
typedef u32 u32x2 __attribute__((ext_vector_type(2)));

__device__ __forceinline__ float bf2f(u16 u) {
  u32 x = ((u32)u) << 16;
  float f;
  __builtin_memcpy(&f, &x, 4);
  return f;
}
__device__ __forceinline__ u16 f2bf(float f) {
  u32 x;
  __builtin_memcpy(&x, &f, 4);
  x += 0x7FFFu + ((x >> 16) & 1u);
  return (u16)(x >> 16);
}
// packed f32 pair -> bf16 pair (lo = a, hi = b)
__device__ __forceinline__ u32 cvtpk(float a, float b) {
  u32 r;
  asm("v_cvt_pk_bf16_f32 %0, %1, %2" : "=v"(r) : "v"(a), "v"(b));
  return r;
}
// r[0] = {a_lo, b_lo}, r[1] = {a_hi, b_hi}
__device__ __forceinline__ u32x2 plswap2(u32 a, u32 b) {
  return __builtin_amdgcn_permlane32_swap(a, b, false, false);
}
// guaranteed single-instruction exp2 (non-volatile: schedulable/CSE-able)
__device__ __forceinline__ float fexp2(float x) {
  float r;
  asm("v_exp_f32 %0, %1" : "=v"(r) : "v"(x));
  return r;
}

#define AS1 __attribute__((address_space(1)))
#define AS3 __attribute__((address_space(3)))
// async global->LDS, 16B per lane; LDS dest is wave-uniform base + lane*16
__device__ __forceinline__ void gload16(const void* g, void* l) {
  __builtin_amdgcn_global_load_lds((AS1 void*)g, (AS3 void*)l, 16, 0, 0);
}

#define MFMA32(a, b, c) __builtin_amdgcn_mfma_f32_32x32x16_bf16(a, b, c, 0, 0, 0)

// ---------------- f32 -> bf16 convert: x (4 parts of 1M) + 4 weight mats ----
__global__ __launch_bounds__(256) void convert_k(
    const float* __restrict__ x, const float* __restrict__ wq, const float* __restrict__ wk,
    const float* __restrict__ wv, const float* __restrict__ wo,
    u16* __restrict__ xb, u16* __restrict__ wqb, u16* __restrict__ wkb,
    u16* __restrict__ wvb, u16* __restrict__ wob) {
  int part = blockIdx.y;
  const float* src;
  u16* dst;
  size_t base = 0;
  if (part < 4) { src = x; dst = xb; base = (size_t)part << 20; }
  else if (part == 4) { src = wq; dst = wqb; }
  else if (part == 5) { src = wk; dst = wkb; }
  else if (part == 6) { src = wv; dst = wvb; }
  else { src = wo; dst = wob; }
  size_t i = base + ((size_t)(blockIdx.x * 256 + threadIdx.x)) * 4;
  float4 v = *(const float4*)(src + i);
  ushort4 o;
  o.x = f2bf(v.x); o.y = f2bf(v.y); o.z = f2bf(v.z); o.w = f2bf(v.w);
  *(ushort4*)(dst + i) = o;
}

// ---------------- 128x128 bf16 GEMM, C = A * B^T (A:[M][K], B:[N][K]) ------
// MODE 0: write f32 row-major [M][N].  MODE 1: write bf16 to [B,H,S,DK].
template <int MODE>
__global__ __launch_bounds__(256) void gemm128(
    const u16* __restrict__ A, const u16* __restrict__ B0, const u16* __restrict__ B1,
    const u16* __restrict__ B2, void* __restrict__ O0, void* __restrict__ O1,
    void* __restrict__ O2) {
  __shared__ alignas(16) u16 As[128 * 64];
  __shared__ alignas(16) u16 Bs[128 * 64];
  int z = blockIdx.z;
  const u16* Bm = (z == 0) ? B0 : ((z == 1) ? B1 : B2);
  void* Om = (z == 0) ? O0 : ((z == 1) ? O1 : O2);
  int m0 = blockIdx.x * 128, n0 = blockIdx.y * 128;
  int t = threadIdx.x;
  int w = t >> 6, lane = t & 63, lr = lane >> 4, lc = lane & 15;
  int wr = w >> 1, wc = w & 1;
  f32x4 acc[4][4] = {};
  int srow = t >> 3;
  int scolb = (t & 7) * 16;
  const char* Ag = (const char*)A;
  const char* Bg = (const char*)Bm;
  for (int k0 = 0; k0 < DMODEL; k0 += 64) {
#pragma unroll
    for (int i = 0; i < 4; i++) {
      gload16(Ag + ((size_t)(m0 + srow + i * 32) * DMODEL + k0) * 2 + scolb,
              (char*)As + i * 4096 + w * 1024);
      gload16(Bg + ((size_t)(n0 + srow + i * 32) * DMODEL + k0) * 2 + scolb,
              (char*)Bs + i * 4096 + w * 1024);
    }
    __syncthreads();
#pragma unroll
    for (int kk = 0; kk < 2; kk++) {
      bf16x8 af[4], bfr[4];
#pragma unroll
      for (int mi = 0; mi < 4; mi++)
        af[mi] = *(const bf16x8*)(As + (wr * 64 + mi * 16 + lc) * 64 + kk * 32 + lr * 8);
#pragma unroll
      for (int ni = 0; ni < 4; ni++)
        bfr[ni] = *(const bf16x8*)(Bs + (wc * 64 + ni * 16 + lc) * 64 + kk * 32 + lr * 8);
#pragma unroll
      for (int mi = 0; mi < 4; mi++)
#pragma unroll
        for (int ni = 0; ni < 4; ni++)
          acc[mi][ni] =
              __builtin_amdgcn_mfma_f32_16x16x32_bf16(af[mi], bfr[ni], acc[mi][ni], 0, 0, 0);
    }
    __syncthreads();
  }
  if (MODE == 0) {
    float* Of = (float*)Om;
#pragma unroll
    for (int mi = 0; mi < 4; mi++)
#pragma unroll
      for (int ni = 0; ni < 4; ni++) {
        int m = m0 + wr * 64 + mi * 16 + lr * 4;
        int n = n0 + wc * 64 + ni * 16 + lc;
#pragma unroll
        for (int r = 0; r < 4; r++) Of[(size_t)(m + r) * DMODEL + n] = acc[mi][ni][r];
      }
  } else {
    u16* Oh = (u16*)Om;
#pragma unroll
    for (int mi = 0; mi < 4; mi++)
#pragma unroll
      for (int ni = 0; ni < 4; ni++) {
        int n = n0 + wc * 64 + ni * 16 + lc;
        int h = n >> 6, d = n & 63;
#pragma unroll
        for (int r = 0; r < 4; r++) {
          int m = m0 + wr * 64 + mi * 16 + lr * 4 + r;
          int b = m >> 11, s = m & 2047;
          Oh[((size_t)(b * NHEADS + h) * S_LEN + s) * DHEAD + d] = f2bf(acc[mi][ni][r]);
        }
      }
  }
}

// ---------------- RoPE in-place on bf16 Q (y=0, with 1/8 scale) and K (y=1) -
__global__ __launch_bounds__(256) void rope_k(u16* __restrict__ Q, u16* __restrict__ K,
                                              const int* __restrict__ pos) {
  int sel = blockIdx.y;
  u16* Aq = sel ? K : Q;
  float oscale = sel ? 1.0f : 0.125f;  // fold 1/sqrt(DK) into Q (exact pow2 in bf16)
  int idx = blockIdx.x * 256 + threadIdx.x;  // 0..262143 (B*H*S*4)
  int r = idx >> 2, seg = idx & 3;
  int b = r >> 15, s = r & 2047;
  float p = (float)pos[(b << 11) + s];
  u16* ptr = Aq + (size_t)r * DHEAD + seg * 16;
  alignas(16) u16 e[16];
  *(uint4*)&e[0] = *(const uint4*)ptr;
  *(uint4*)&e[8] = *(const uint4*)(ptr + 8);
#pragma unroll
  for (int j = 0; j < 8; j++) {
    int i = seg * 8 + j;  // pair index 0..31
    float fr = exp2f(-0.4152410118407687f * (float)i);  // theta^(-2i/64)
    float ang = p * fr;
    float sn, cs;
    __sincosf(ang, &sn, &cs);
    float ev = bf2f(e[2 * j]), ov = bf2f(e[2 * j + 1]);
    e[2 * j] = f2bf((ev * cs - ov * sn) * oscale);
    e[2 * j + 1] = f2bf((ev * sn + ov * cs) * oscale);
  }
  *(uint4*)ptr = *(const uint4*)&e[0];
  *(uint4*)(ptr + 8) = *(const uint4*)&e[8];
}

// ---------------- V [B,H,S,DK] -> VT [B,H,DK,S] -----------------------------
__global__ __launch_bounds__(256) void transpose_v(const u16* __restrict__ V,
                                                   u16* __restrict__ VT) {
  __shared__ alignas(16) u16 T[64][72];
  int kv0 = blockIdx.x * 64;
  int bh = blockIdx.y;
  int t = threadIdx.x;
  int rr = t >> 3, c8 = (t & 7) * 8;
  const u16* src = V + ((size_t)bh * S_LEN + kv0) * DHEAD;
#pragma unroll
  for (int i = 0; i < 2; i++) {
    const u16* sp = src + (size_t)(rr + i * 32) * DHEAD + c8;
    *(uint2*)&T[rr + i * 32][c8] = *(const uint2*)sp;
    *(uint2*)&T[rr + i * 32][c8 + 4] = *(const uint2*)(sp + 4);
  }
  __syncthreads();
  u16* dst = VT + (size_t)bh * DHEAD * S_LEN + kv0;
#pragma unroll
  for (int i = 0; i < 2; i++) {
    int d = rr + i * 32;
    ushort4 a, c;
    a.x = T[c8 + 0][d]; a.y = T[c8 + 1][d]; a.z = T[c8 + 2][d]; a.w = T[c8 + 3][d];
    c.x = T[c8 + 4][d]; c.y = T[c8 + 5][d]; c.z = T[c8 + 6][d]; c.w = T[c8 + 7][d];
    *(ushort4*)(dst + (size_t)d * S_LEN + c8) = a;
    *(ushort4*)(dst + (size_t)d * S_LEN + c8 + 4) = c;
  }
}

// ---------------- causal flash attention, v5: waveflat, no LDS, no barriers -
// One wave (64 thr) per block = one 32-row q-tile. K/V read directly from
// global (L2-resident: bh%8 == XCD via round-robin dispatch -> 4 heads/XCD
// = 3MB working set). Per tile: issue V loads -> QK MFMA -> issue K(nt+1)
// prefetch -> in-register softmax (covers V latency) -> PV MFMA. Counted
// vmcnt by compiler; no drain-to-0 in loop. Balanced grid: y -> qt map
// (y<32 ? 63-y : y-32) gives every CU a constant qt-sum; heavy waves first.
struct AttnState {
  const u16 *Kp, *Vp;
  bf16x8 qf[4];
  f32x16 oacc[2];
  float mrun, lrun;
  int ntl, qrow, h;
};

__device__ __forceinline__ void attn_tile(AttnState& st, bf16x8 (&cur)[8],
                                          bf16x8 (&nxt)[8], int nt) {
  const float L2E = 1.4426950408889634f;
  int kv0 = nt * 64;
  // V A-frags for this tile (issued first; consumed only after softmax)
  bf16x8 vf[8];
#pragma unroll
  for (int f = 0; f < 8; f++)
    vf[f] = *(const bf16x8*)(st.Vp + (size_t)((f >> 2) * 32) * S_LEN + kv0 + (f & 3) * 16);
  // S^T = K * Q^T
  f32x16 sacc[2] = {};
  __builtin_amdgcn_s_setprio(1);
#pragma unroll
  for (int kt = 0; kt < 4; kt++) {
    sacc[0] = MFMA32(cur[kt], st.qf[kt], sacc[0]);
    sacc[1] = MFMA32(cur[4 + kt], st.qf[kt], sacc[1]);
  }
  __builtin_amdgcn_s_setprio(0);
  // prefetch K(nt+1) (stays in flight across the softmax + PV)
  if (nt < st.ntl) {
    const u16* Kn = st.Kp + (size_t)(kv0 + 64) * DHEAD;
#pragma unroll
    for (int f = 0; f < 8; f++)
      nxt[f] = *(const bf16x8*)(Kn + (size_t)((f >> 2) * 32) * DHEAD + (f & 3) * 16);
  }
  if (nt == st.ntl) {  // causal mask on the diagonal tile
#pragma unroll
    for (int r = 0; r < 16; r++) {
      int kvb = kv0 + (r & 3) + 8 * (r >> 2) + 4 * st.h;
      if (kvb > st.qrow) sacc[0][r] = -1e30f;
      if (kvb + 32 > st.qrow) sacc[1][r] = -1e30f;
    }
  }
  // row max: in-register tree over own half + cross-half shfl
  float t8[8];
#pragma unroll
  for (int r = 0; r < 8; r++)
    t8[r] = fmaxf(fmaxf(sacc[0][r], sacc[0][r + 8]), fmaxf(sacc[1][r], sacc[1][r + 8]));
  float t4a = fmaxf(t8[0], t8[4]), t4b = fmaxf(t8[1], t8[5]);
  float t4c = fmaxf(t8[2], t8[6]), t4d = fmaxf(t8[3], t8[7]);
  float mx = fmaxf(fmaxf(t4a, t4b), fmaxf(t4c, t4d));
  mx = fmaxf(mx, __shfl_xor(mx, 32));
  // defer-max: only rescale when max grew by > 8*ln2
  bool up = mx > st.mrun + 5.5451774444795624f;
  if (__any(up)) {
    float newm = up ? mx : st.mrun;
    float scl = fexp2((st.mrun - newm) * L2E);
    st.mrun = newm;
    st.lrun *= scl;
#pragma unroll
    for (int r = 0; r < 16; r++) { st.oacc[0][r] *= scl; st.oacc[1][r] *= scl; }
  }
  float nm2 = -st.mrun * L2E;
#pragma unroll
  for (int r = 0; r < 16; r++) {
    sacc[0][r] = fexp2(__builtin_fmaf(sacc[0][r], L2E, nm2));
    sacc[1][r] = fexp2(__builtin_fmaf(sacc[1][r], L2E, nm2));
  }
  float u8[8];
#pragma unroll
  for (int r = 0; r < 8; r++)
    u8[r] = (sacc[0][r] + sacc[0][r + 8]) + (sacc[1][r] + sacc[1][r + 8]);
  st.lrun += ((u8[0] + u8[4]) + (u8[1] + u8[5])) + ((u8[2] + u8[6]) + (u8[3] + u8[7]));
  // P^T -> bf16 B-frags
  u32x4 pa[4];
#pragma unroll
  for (int tau = 0; tau < 2; tau++) {
    u32x2 rA = plswap2(cvtpk(sacc[tau][0], sacc[tau][1]), cvtpk(sacc[tau][4], sacc[tau][5]));
    pa[2 * tau][0] = rA[0]; pa[2 * tau][2] = rA[1];
    u32x2 rC = plswap2(cvtpk(sacc[tau][2], sacc[tau][3]), cvtpk(sacc[tau][6], sacc[tau][7]));
    pa[2 * tau][1] = rC[0]; pa[2 * tau][3] = rC[1];
    u32x2 rA1 = plswap2(cvtpk(sacc[tau][8], sacc[tau][9]), cvtpk(sacc[tau][12], sacc[tau][13]));
    pa[2 * tau + 1][0] = rA1[0]; pa[2 * tau + 1][2] = rA1[1];
    u32x2 rC1 = plswap2(cvtpk(sacc[tau][10], sacc[tau][11]), cvtpk(sacc[tau][14], sacc[tau][15]));
    pa[2 * tau + 1][1] = rC1[0]; pa[2 * tau + 1][3] = rC1[1];
  }
  // O^T += V^T * P^T
  __builtin_amdgcn_s_setprio(1);
#pragma unroll
  for (int kt = 0; kt < 4; kt++) {
    bf16x8 pb = __builtin_bit_cast(bf16x8, pa[kt]);
    st.oacc[0] = MFMA32(vf[kt], pb, st.oacc[0]);
    st.oacc[1] = MFMA32(vf[4 + kt], pb, st.oacc[1]);
  }
  __builtin_amdgcn_s_setprio(0);
}

__global__ __launch_bounds__(64) void attn_k(const u16* __restrict__ Q,
                                             const u16* __restrict__ K,
                                             const u16* __restrict__ VT,
                                             u16* __restrict__ O) {
  int bh = blockIdx.x;  // fast dim -> bh%8 tracks XCD (round-robin dispatch)
  int yy = blockIdx.y;
  int qt = (yy < 32) ? (63 - yy) : (yy - 32);  // balanced heavy/light pairing
  int lane = threadIdx.x & 63;
  int ql = lane & 31, h = lane >> 5;
  size_t base = (size_t)bh * (S_LEN * DHEAD);
  AttnState st;
  st.h = h;
  st.qrow = qt * 32 + ql;
  st.ntl = qt >> 1;
  st.mrun = -1e30f;
  st.lrun = 0.0f;
  st.Kp = K + base + (size_t)ql * DHEAD + h * 8;
  st.Vp = VT + ((size_t)bh * DHEAD + ql) * S_LEN + h * 8;
  const u16* Qp = Q + base + (size_t)st.qrow * DHEAD + h * 8;
#pragma unroll
  for (int kt = 0; kt < 4; kt++) st.qf[kt] = *(const bf16x8*)(Qp + kt * 16);
  st.oacc[0] = f32x16{};
  st.oacc[1] = f32x16{};
  bf16x8 ka[8], kb_[8];
#pragma unroll
  for (int f = 0; f < 8; f++)
    ka[f] = *(const bf16x8*)(st.Kp + (size_t)((f >> 2) * 32) * DHEAD + (f & 3) * 16);
  for (int nt = 0; nt <= st.ntl; nt += 2) {
    attn_tile(st, ka, kb_, nt);
    if (nt + 1 <= st.ntl) attn_tile(st, kb_, ka, nt + 1);
  }
  // combine cross-half row-sum, normalize, packed 8B stores
  float lsum = st.lrun + __shfl_xor(st.lrun, 32);
  float inv = 1.0f / lsum;
  int b = bh >> 4, hd = bh & 15;
  u16* Orow = O + ((size_t)(b * S_LEN + st.qrow)) * DMODEL + hd * 64;
#pragma unroll
  for (int dt = 0; dt < 2; dt++)
#pragma unroll
    for (int rr = 0; rr < 4; rr++) {
      u32 lo = cvtpk(st.oacc[dt][4 * rr + 0] * inv, st.oacc[dt][4 * rr + 1] * inv);
      u32 hi = cvtpk(st.oacc[dt][4 * rr + 2] * inv, st.oacc[dt][4 * rr + 3] * inv);
      uint2 pk;
      pk.x = lo;
      pk.y = hi;
      *(uint2*)(Orow + 32 * dt + 8 * rr + 4 * h) = pk;
    }
}

// ---------------- launch -----------------------------------------------------
extern "C" void kernel_launch(void* const* d_in, const int* in_sizes, int n_in,
                              void* d_out, int out_size, void* d_ws, size_t ws_size,
                              hipStream_t stream) {
  (void)in_sizes; (void)n_in; (void)out_size; (void)ws_size;
  const float* x = (const float*)d_in[0];
  const int* tpos = (const int*)d_in[1];
  const float* Wq = (const float*)d_in[2];
  const float* Wk = (const float*)d_in[3];
  const float* Wv = (const float*)d_in[4];
  const float* Wo = (const float*)d_in[5];
  char* ws = (char*)d_ws;
  // workspace map (56 MB total)
  u16* xb  = (u16*)(ws + ((size_t)0 << 20));   // 8 MB  [4096][1024] bf16
  u16* wqb = (u16*)(ws + ((size_t)8 << 20));   // 2 MB
  u16* wkb = (u16*)(ws + ((size_t)10 << 20));  // 2 MB
  u16* wvb = (u16*)(ws + ((size_t)12 << 20));  // 2 MB
  u16* wob = (u16*)(ws + ((size_t)14 << 20));  // 2 MB
  u16* Qb  = (u16*)(ws + ((size_t)16 << 20));  // 8 MB  [B,H,S,DK]
  u16* Kb  = (u16*)(ws + ((size_t)24 << 20));  // 8 MB
  u16* Vb  = (u16*)(ws + ((size_t)32 << 20));  // 8 MB
  u16* VTb = (u16*)(ws + ((size_t)40 << 20));  // 8 MB  [B,H,DK,S]
  u16* Ob  = (u16*)(ws + ((size_t)48 << 20));  // 8 MB  [B,S,DMODEL] bf16

  convert_k<<<dim3(1024, 8), 256, 0, stream>>>(x, Wq, Wk, Wv, Wo, xb, wqb, wkb, wvb, wob);
  gemm128<1><<<dim3(32, 8, 3), 256, 0, stream>>>(xb, wqb, wkb, wvb,
                                                 (void*)Qb, (void*)Kb, (void*)Vb);
  rope_k<<<dim3(1024, 2), 256, 0, stream>>>(Qb, Kb, tpos);
  transpose_v<<<dim3(32, 32), 256, 0, stream>>>(Vb, VTb);
  attn_k<<<dim3(32, 64), 64, 0, stream>>>(Qb, Kb, VTb, Ob);
  gemm128<0><<<dim3(32, 8, 1), 256, 0, stream>>>(Ob, wob, wob, wob, d_out, d_out, d_out);
}

// Round 6
// 165.393 us; speedup vs baseline: 1.0050x; 1.0050x over previous
//
#include <hip/hip_runtime.h>
#include <stdint.h>

#define S_LEN 2048
#define NHEADS 16
#define DHEAD 64
#define DMODEL 1024

typedef unsigned short u16;
typedef unsigned int u32;
typedef __bf16 bf16x8 __attribute__((ext_vector_type(8)));
typedef float f32x4 __attribute__((ext_vector_type(4)));
typedef float f32x16 __attribute__((ext_vector_type(16)));
typedef u32 u32x4 __attribute__((ext_vector_type(4)));
typedef u32 u32x2 __attribute__((ext_vector_type(2)));

__device__ __forceinline__ float bf2f(u16 u) {
  u32 x = ((u32)u) << 16;
  float f;
  __builtin_memcpy(&f, &x, 4);
  return f;
}
__device__ __forceinline__ u16 f2bf(float f) {
  u32 x;
  __builtin_memcpy(&x, &f, 4);
  x += 0x7FFFu + ((x >> 16) & 1u);
  return (u16)(x >> 16);
}
// packed f32 pair -> bf16 pair (lo = a, hi = b)
__device__ __forceinline__ u32 cvtpk(float a, float b) {
  u32 r;
  asm("v_cvt_pk_bf16_f32 %0, %1, %2" : "=v"(r) : "v"(a), "v"(b));
  return r;
}
// r[0] = {a_lo, b_lo}, r[1] = {a_hi, b_hi}
__device__ __forceinline__ u32x2 plswap2(u32 a, u32 b) {
  return __builtin_amdgcn_permlane32_swap(a, b, false, false);
}
// single-instruction exp2
__device__ __forceinline__ float fexp2(float x) {
  float r;
  asm("v_exp_f32 %0, %1" : "=v"(r) : "v"(x));
  return r;
}

#define AS1 __attribute__((address_space(1)))
#define AS3 __attribute__((address_space(3)))
__device__ __forceinline__ void gload16(const void* g, void* l) {
  __builtin_amdgcn_global_load_lds((AS1 void*)g, (AS3 void*)l, 16, 0, 0);
}

#define MFMA32(a, b, c) __builtin_amdgcn_mfma_f32_32x32x16_bf16(a, b, c, 0, 0, 0)

// ---------------- f32 -> bf16 convert: x (4 parts of 1M) + 4 weight mats ----
__global__ __launch_bounds__(256) void convert_k(
    const float* __restrict__ x, const float* __restrict__ wq, const float* __restrict__ wk,
    const float* __restrict__ wv, const float* __restrict__ wo,
    u16* __restrict__ xb, u16* __restrict__ wqb, u16* __restrict__ wkb,
    u16* __restrict__ wvb, u16* __restrict__ wob) {
  int part = blockIdx.y;
  const float* src;
  u16* dst;
  size_t base = 0;
  if (part < 4) { src = x; dst = xb; base = (size_t)part << 20; }
  else if (part == 4) { src = wq; dst = wqb; }
  else if (part == 5) { src = wk; dst = wkb; }
  else if (part == 6) { src = wv; dst = wvb; }
  else { src = wo; dst = wob; }
  size_t i = base + ((size_t)(blockIdx.x * 256 + threadIdx.x)) * 4;
  float4 v = *(const float4*)(src + i);
  ushort4 o;
  o.x = f2bf(v.x); o.y = f2bf(v.y); o.z = f2bf(v.z); o.w = f2bf(v.w);
  *(ushort4*)(dst + i) = o;
}

// ---------------- 128x128 bf16 GEMM, C = A * B^T (A:[M][K], B:[N][K]) ------
template <int MODE>
__global__ __launch_bounds__(256) void gemm128(
    const u16* __restrict__ A, const u16* __restrict__ B0, const u16* __restrict__ B1,
    const u16* __restrict__ B2, void* __restrict__ O0, void* __restrict__ O1,
    void* __restrict__ O2) {
  __shared__ alignas(16) u16 As[128 * 64];
  __shared__ alignas(16) u16 Bs[128 * 64];
  int z = blockIdx.z;
  const u16* Bm = (z == 0) ? B0 : ((z == 1) ? B1 : B2);
  void* Om = (z == 0) ? O0 : ((z == 1) ? O1 : O2);
  int m0 = blockIdx.x * 128, n0 = blockIdx.y * 128;
  int t = threadIdx.x;
  int w = t >> 6, lane = t & 63, lr = lane >> 4, lc = lane & 15;
  int wr = w >> 1, wc = w & 1;
  f32x4 acc[4][4] = {};
  int srow = t >> 3;
  int scolb = (t & 7) * 16;
  const char* Ag = (const char*)A;
  const char* Bg = (const char*)Bm;
  for (int k0 = 0; k0 < DMODEL; k0 += 64) {
#pragma unroll
    for (int i = 0; i < 4; i++) {
      gload16(Ag + ((size_t)(m0 + srow + i * 32) * DMODEL + k0) * 2 + scolb,
              (char*)As + i * 4096 + w * 1024);
      gload16(Bg + ((size_t)(n0 + srow + i * 32) * DMODEL + k0) * 2 + scolb,
              (char*)Bs + i * 4096 + w * 1024);
    }
    __syncthreads();
#pragma unroll
    for (int kk = 0; kk < 2; kk++) {
      bf16x8 af[4], bfr[4];
#pragma unroll
      for (int mi = 0; mi < 4; mi++)
        af[mi] = *(const bf16x8*)(As + (wr * 64 + mi * 16 + lc) * 64 + kk * 32 + lr * 8);
#pragma unroll
      for (int ni = 0; ni < 4; ni++)
        bfr[ni] = *(const bf16x8*)(Bs + (wc * 64 + ni * 16 + lc) * 64 + kk * 32 + lr * 8);
#pragma unroll
      for (int mi = 0; mi < 4; mi++)
#pragma unroll
        for (int ni = 0; ni < 4; ni++)
          acc[mi][ni] =
              __builtin_amdgcn_mfma_f32_16x16x32_bf16(af[mi], bfr[ni], acc[mi][ni], 0, 0, 0);
    }
    __syncthreads();
  }
  if (MODE == 0) {
    float* Of = (float*)Om;
#pragma unroll
    for (int mi = 0; mi < 4; mi++)
#pragma unroll
      for (int ni = 0; ni < 4; ni++) {
        int m = m0 + wr * 64 + mi * 16 + lr * 4;
        int n = n0 + wc * 64 + ni * 16 + lc;
#pragma unroll
        for (int r = 0; r < 4; r++) Of[(size_t)(m + r) * DMODEL + n] = acc[mi][ni][r];
      }
  } else {
    u16* Oh = (u16*)Om;
#pragma unroll
    for (int mi = 0; mi < 4; mi++)
#pragma unroll
      for (int ni = 0; ni < 4; ni++) {
        int n = n0 + wc * 64 + ni * 16 + lc;
        int h = n >> 6, d = n & 63;
#pragma unroll
        for (int r = 0; r < 4; r++) {
          int m = m0 + wr * 64 + mi * 16 + lr * 4 + r;
          int b = m >> 11, s = m & 2047;
          Oh[((size_t)(b * NHEADS + h) * S_LEN + s) * DHEAD + d] = f2bf(acc[mi][ni][r]);
        }
      }
  }
}

// ---------------- RoPE in-place on bf16 Q (y=0, with 1/8 scale) and K (y=1) -
__global__ __launch_bounds__(256) void rope_k(u16* __restrict__ Q, u16* __restrict__ K,
                                              const int* __restrict__ pos) {
  int sel = blockIdx.y;
  u16* Aq = sel ? K : Q;
  float oscale = sel ? 1.0f : 0.125f;
  int idx = blockIdx.x * 256 + threadIdx.x;
  int r = idx >> 2, seg = idx & 3;
  int b = r >> 15, s = r & 2047;
  float p = (float)pos[(b << 11) + s];
  u16* ptr = Aq + (size_t)r * DHEAD + seg * 16;
  alignas(16) u16 e[16];
  *(uint4*)&e[0] = *(const uint4*)ptr;
  *(uint4*)&e[8] = *(const uint4*)(ptr + 8);
#pragma unroll
  for (int j = 0; j < 8; j++) {
    int i = seg * 8 + j;
    float fr = exp2f(-0.4152410118407687f * (float)i);
    float ang = p * fr;
    float sn, cs;
    __sincosf(ang, &sn, &cs);
    float ev = bf2f(e[2 * j]), ov = bf2f(e[2 * j + 1]);
    e[2 * j] = f2bf((ev * cs - ov * sn) * oscale);
    e[2 * j + 1] = f2bf((ev * sn + ov * cs) * oscale);
  }
  *(uint4*)ptr = *(const uint4*)&e[0];
  *(uint4*)(ptr + 8) = *(const uint4*)&e[8];
}

// ---------------- V [B,H,S,DK] -> VT [B,H,DK,S] -----------------------------
__global__ __launch_bounds__(256) void transpose_v(const u16* __restrict__ V,
                                                   u16* __restrict__ VT) {
  __shared__ alignas(16) u16 T[64][72];
  int kv0 = blockIdx.x * 64;
  int bh = blockIdx.y;
  int t = threadIdx.x;
  int rr = t >> 3, c8 = (t & 7) * 8;
  const u16* src = V + ((size_t)bh * S_LEN + kv0) * DHEAD;
#pragma unroll
  for (int i = 0; i < 2; i++) {
    const u16* sp = src + (size_t)(rr + i * 32) * DHEAD + c8;
    *(uint2*)&T[rr + i * 32][c8] = *(const uint2*)sp;
    *(uint2*)&T[rr + i * 32][c8 + 4] = *(const uint2*)(sp + 4);
  }
  __syncthreads();
  u16* dst = VT + (size_t)bh * DHEAD * S_LEN + kv0;
#pragma unroll
  for (int i = 0; i < 2; i++) {
    int d = rr + i * 32;
    ushort4 a, c;
    a.x = T[c8 + 0][d]; a.y = T[c8 + 1][d]; a.z = T[c8 + 2][d]; a.w = T[c8 + 3][d];
    c.x = T[c8 + 4][d]; c.y = T[c8 + 5][d]; c.z = T[c8 + 6][d]; c.w = T[c8 + 7][d];
    *(ushort4*)(dst + (size_t)d * S_LEN + c8) = a;
    *(ushort4*)(dst + (size_t)d * S_LEN + c8 + 4) = c;
  }
}

// ---------------- causal flash attention, v6: wave-flat + split-K ----------
// One wave per work item; KV axis split into fixed 16-tile (1024-kv) chunks:
//   y in [0,32):  qt = 32+y,  kv tiles [0,16)      -> partial slot chunk 0
//   y in [32,64): qt = 95-y,  kv tiles [16, qt/2]  -> partial slot chunk 1
//                                                    (qt descending = heavy first)
//   y in [64,96): qt = 95-y,  kv tiles [0, qt/2]   -> direct write (qt < 32)
// 3072 uniform-ish waves (12/CU demand vs 8/CU residency cap) -> no tail.
// Partials (unnormalized O in bf16 frag layout + f32 m,l) in dead xb region.
__global__ __launch_bounds__(64) void attn_k(const u16* __restrict__ Q,
                                             const u16* __restrict__ K,
                                             const u16* __restrict__ VT,
                                             u16* __restrict__ O,
                                             char* __restrict__ PB) {
  int bh = blockIdx.x;  // fast dim -> bh%8 tracks XCD
  int y = blockIdx.y;
  int qt, nt0, nt1, chunk;
  bool partial;
  if (y < 32) { qt = 32 + y; nt0 = 0; nt1 = 15; chunk = 0; partial = true; }
  else if (y < 64) { qt = 95 - y; nt0 = 16; nt1 = qt >> 1; chunk = 1; partial = true; }
  else { qt = 95 - y; nt0 = 0; nt1 = qt >> 1; chunk = 0; partial = false; }
  int ntd = qt >> 1;  // diagonal tile index (never reached by chunk-0 waves)
  int lane = threadIdx.x & 63;
  int ql = lane & 31, h = lane >> 5;
  size_t base = (size_t)bh * (S_LEN * DHEAD);
  int qrow = qt * 32 + ql;
  const u16* Kp = K + base + (size_t)ql * DHEAD + h * 8;
  const u16* Vp = VT + ((size_t)bh * DHEAD + ql) * S_LEN + h * 8;
  const u16* Qp = Q + base + (size_t)qrow * DHEAD + h * 8;
  bf16x8 qf[4];
#pragma unroll
  for (int kt = 0; kt < 4; kt++) qf[kt] = *(const bf16x8*)(Qp + kt * 16);
  f32x16 oacc[2] = {};
  float mrun = -1e30f, lrun = 0.0f;
  const float L2E = 1.4426950408889634f;
#pragma unroll 1
  for (int nt = nt0; nt <= nt1; ++nt) {
    int kv0 = nt * 64;
    bf16x8 kf[8];
#pragma unroll
    for (int f = 0; f < 8; f++)
      kf[f] = *(const bf16x8*)(Kp + (size_t)(kv0 + (f >> 2) * 32) * DHEAD + (f & 3) * 16);
    // S^T = K * Q^T
    f32x16 sacc[2] = {};
    __builtin_amdgcn_s_setprio(1);
#pragma unroll
    for (int kt = 0; kt < 4; kt++) {
      sacc[0] = MFMA32(kf[kt], qf[kt], sacc[0]);
      sacc[1] = MFMA32(kf[4 + kt], qf[kt], sacc[1]);
    }
    __builtin_amdgcn_s_setprio(0);
    // V frags (issued now; consumed after softmax — latency hidden)
    bf16x8 vf[8];
#pragma unroll
    for (int f = 0; f < 8; f++)
      vf[f] = *(const bf16x8*)(Vp + (size_t)((f >> 2) * 32) * S_LEN + kv0 + (f & 3) * 16);
    if (nt == ntd) {  // causal mask on the diagonal tile
#pragma unroll
      for (int r = 0; r < 16; r++) {
        int kvb = kv0 + (r & 3) + 8 * (r >> 2) + 4 * h;
        if (kvb > qrow) sacc[0][r] = -1e30f;
        if (kvb + 32 > qrow) sacc[1][r] = -1e30f;
      }
    }
    // row max: in-register tree + cross-half shfl
    float t8[8];
#pragma unroll
    for (int r = 0; r < 8; r++)
      t8[r] = fmaxf(fmaxf(sacc[0][r], sacc[0][r + 8]), fmaxf(sacc[1][r], sacc[1][r + 8]));
    float t4a = fmaxf(t8[0], t8[4]), t4b = fmaxf(t8[1], t8[5]);
    float t4c = fmaxf(t8[2], t8[6]), t4d = fmaxf(t8[3], t8[7]);
    float mx = fmaxf(fmaxf(t4a, t4b), fmaxf(t4c, t4d));
    mx = fmaxf(mx, __shfl_xor(mx, 32));
    bool up = mx > mrun + 5.5451774444795624f;  // defer-max, THR=8*ln2
    if (__any(up)) {
      float newm = up ? mx : mrun;
      float scl = fexp2((mrun - newm) * L2E);
      mrun = newm;
      lrun *= scl;
#pragma unroll
      for (int r = 0; r < 16; r++) { oacc[0][r] *= scl; oacc[1][r] *= scl; }
    }
    float nm2 = -mrun * L2E;
#pragma unroll
    for (int r = 0; r < 16; r++) {
      sacc[0][r] = fexp2(__builtin_fmaf(sacc[0][r], L2E, nm2));
      sacc[1][r] = fexp2(__builtin_fmaf(sacc[1][r], L2E, nm2));
    }
    float u8[8];
#pragma unroll
    for (int r = 0; r < 8; r++)
      u8[r] = (sacc[0][r] + sacc[0][r + 8]) + (sacc[1][r] + sacc[1][r + 8]);
    lrun += ((u8[0] + u8[4]) + (u8[1] + u8[5])) + ((u8[2] + u8[6]) + (u8[3] + u8[7]));
    // P^T -> bf16 B-frags
    u32x4 pa[4];
#pragma unroll
    for (int tau = 0; tau < 2; tau++) {
      u32x2 rA = plswap2(cvtpk(sacc[tau][0], sacc[tau][1]), cvtpk(sacc[tau][4], sacc[tau][5]));
      pa[2 * tau][0] = rA[0]; pa[2 * tau][2] = rA[1];
      u32x2 rC = plswap2(cvtpk(sacc[tau][2], sacc[tau][3]), cvtpk(sacc[tau][6], sacc[tau][7]));
      pa[2 * tau][1] = rC[0]; pa[2 * tau][3] = rC[1];
      u32x2 rA1 = plswap2(cvtpk(sacc[tau][8], sacc[tau][9]), cvtpk(sacc[tau][12], sacc[tau][13]));
      pa[2 * tau + 1][0] = rA1[0]; pa[2 * tau + 1][2] = rA1[1];
      u32x2 rC1 = plswap2(cvtpk(sacc[tau][10], sacc[tau][11]), cvtpk(sacc[tau][14], sacc[tau][15]));
      pa[2 * tau + 1][1] = rC1[0]; pa[2 * tau + 1][3] = rC1[1];
    }
    // O^T += V^T * P^T
    __builtin_amdgcn_s_setprio(1);
#pragma unroll
    for (int kt = 0; kt < 4; kt++) {
      bf16x8 pb = __builtin_bit_cast(bf16x8, pa[kt]);
      oacc[0] = MFMA32(vf[kt], pb, oacc[0]);
      oacc[1] = MFMA32(vf[4 + kt], pb, oacc[1]);
    }
    __builtin_amdgcn_s_setprio(0);
  }
  float lsum = lrun + __shfl_xor(lrun, 32);
  if (!partial) {
    float inv = 1.0f / lsum;
    int b = bh >> 4, hd = bh & 15;
    u16* Orow = O + ((size_t)(b * S_LEN + qrow)) * DMODEL + hd * 64;
#pragma unroll
    for (int dt = 0; dt < 2; dt++)
#pragma unroll
      for (int rr = 0; rr < 4; rr++) {
        uint2 pk;
        pk.x = cvtpk(oacc[dt][4 * rr + 0] * inv, oacc[dt][4 * rr + 1] * inv);
        pk.y = cvtpk(oacc[dt][4 * rr + 2] * inv, oacc[dt][4 * rr + 3] * inv);
        *(uint2*)(Orow + 32 * dt + 8 * rr + 4 * h) = pk;
      }
  } else {
    // unnormalized partial: O words (bf16, frag layout) + per-row {m, l}
    int pi = (((bh << 5) + (qt - 32)) << 1) + chunk;
    char* p = PB + (size_t)pi * 4352;
    u32x4 wv[4];
#pragma unroll
    for (int dt = 0; dt < 2; dt++)
#pragma unroll
      for (int rr = 0; rr < 4; rr++) {
        int wi = dt * 8 + rr * 2;
        ((u32*)wv)[wi] = cvtpk(oacc[dt][4 * rr + 0], oacc[dt][4 * rr + 1]);
        ((u32*)wv)[wi + 1] = cvtpk(oacc[dt][4 * rr + 2], oacc[dt][4 * rr + 3]);
      }
#pragma unroll
    for (int i = 0; i < 4; i++) *(u32x4*)(p + lane * 64 + i * 16) = wv[i];
    if (lane < 32) {
      float2 ml;
      ml.x = mrun;
      ml.y = lsum;
      *(float2*)(p + 4096 + ql * 8) = ml;
    }
  }
}

// ---------------- merge split-K partials (qt >= 32) -------------------------
__global__ __launch_bounds__(256) void merge_k(const char* __restrict__ PB,
                                               u16* __restrict__ O) {
  int bh = blockIdx.x;
  int w = threadIdx.x >> 6, lane = threadIdx.x & 63;
  int ql = lane & 31, h = lane >> 5;
  int qt = 32 + (blockIdx.y * 4 + w);
  const float L2E = 1.4426950408889634f;
  const char* p0 = PB + (size_t)((((bh << 5) + (qt - 32)) << 1)) * 4352;
  const char* p1 = p0 + 4352;
  float2 ml0 = *(const float2*)(p0 + 4096 + ql * 8);
  float2 ml1 = *(const float2*)(p1 + 4096 + ql * 8);
  float m = fmaxf(ml0.x, ml1.x);
  float s0 = fexp2((ml0.x - m) * L2E);
  float s1 = fexp2((ml1.x - m) * L2E);
  float inv = 1.0f / (ml0.y * s0 + ml1.y * s1);
  s0 *= inv;
  s1 *= inv;
  u32x4 a0[4], a1[4];
#pragma unroll
  for (int i = 0; i < 4; i++) {
    a0[i] = *(const u32x4*)(p0 + lane * 64 + i * 16);
    a1[i] = *(const u32x4*)(p1 + lane * 64 + i * 16);
  }
  int qrow = qt * 32 + ql;
  int b = bh >> 4, hd = bh & 15;
  u16* Orow = O + ((size_t)(b * S_LEN + qrow)) * DMODEL + hd * 64;
#pragma unroll
  for (int dt = 0; dt < 2; dt++)
#pragma unroll
    for (int rr = 0; rr < 4; rr++) {
      int wi = dt * 8 + rr * 2;
      u32 x0 = ((const u32*)a0)[wi], x1 = ((const u32*)a1)[wi];
      u32 y0 = ((const u32*)a0)[wi + 1], y1 = ((const u32*)a1)[wi + 1];
      float o0 = bf2f((u16)x0) * s0 + bf2f((u16)x1) * s1;
      float o1 = bf2f((u16)(x0 >> 16)) * s0 + bf2f((u16)(x1 >> 16)) * s1;
      float o2 = bf2f((u16)y0) * s0 + bf2f((u16)y1) * s1;
      float o3 = bf2f((u16)(y0 >> 16)) * s0 + bf2f((u16)(y1 >> 16)) * s1;
      uint2 pk;
      pk.x = cvtpk(o0, o1);
      pk.y = cvtpk(o2, o3);
      *(uint2*)(Orow + 32 * dt + 8 * rr + 4 * h) = pk;
    }
}

// ---------------- launch -----------------------------------------------------
extern "C" void kernel_launch(void* const* d_in, const int* in_sizes, int n_in,
                              void* d_out, int out_size, void* d_ws, size_t ws_size,
                              hipStream_t stream) {
  (void)in_sizes; (void)n_in; (void)out_size; (void)ws_size;
  const float* x = (const float*)d_in[0];
  const int* tpos = (const int*)d_in[1];
  const float* Wq = (const float*)d_in[2];
  const float* Wk = (const float*)d_in[3];
  const float* Wv = (const float*)d_in[4];
  const float* Wo = (const float*)d_in[5];
  char* ws = (char*)d_ws;
  // workspace map (56 MB total). xb/wqb/wkb/wvb are DEAD after gemm<1>;
  // attn split-K partials (8.5 MB) reuse that region (wob at 14 MB untouched).
  u16* xb  = (u16*)(ws + ((size_t)0 << 20));   // 8 MB  [4096][1024] bf16
  u16* wqb = (u16*)(ws + ((size_t)8 << 20));   // 2 MB
  u16* wkb = (u16*)(ws + ((size_t)10 << 20));  // 2 MB
  u16* wvb = (u16*)(ws + ((size_t)12 << 20));  // 2 MB
  u16* wob = (u16*)(ws + ((size_t)14 << 20));  // 2 MB
  u16* Qb  = (u16*)(ws + ((size_t)16 << 20));  // 8 MB  [B,H,S,DK]
  u16* Kb  = (u16*)(ws + ((size_t)24 << 20));  // 8 MB
  u16* Vb  = (u16*)(ws + ((size_t)32 << 20));  // 8 MB
  u16* VTb = (u16*)(ws + ((size_t)40 << 20));  // 8 MB  [B,H,DK,S]
  u16* Ob  = (u16*)(ws + ((size_t)48 << 20));  // 8 MB  [B,S,DMODEL] bf16
  char* PB = ws;                               // 8.5 MB partials (dead xb/wqb)

  convert_k<<<dim3(1024, 8), 256, 0, stream>>>(x, Wq, Wk, Wv, Wo, xb, wqb, wkb, wvb, wob);
  gemm128<1><<<dim3(32, 8, 3), 256, 0, stream>>>(xb, wqb, wkb, wvb,
                                                 (void*)Qb, (void*)Kb, (void*)Vb);
  rope_k<<<dim3(1024, 2), 256, 0, stream>>>(Qb, Kb, tpos);
  transpose_v<<<dim3(32, 32), 256, 0, stream>>>(Vb, VTb);
  attn_k<<<dim3(32, 96), 64, 0, stream>>>(Qb, Kb, VTb, Ob, PB);
  merge_k<<<dim3(32, 8), 256, 0, stream>>>(PB, Ob);
  gemm128<0><<<dim3(32, 8, 1), 256, 0, stream>>>(Ob, wob, wob, wob, d_out, d_out, d_out);
}